// Round 5
// baseline (11070.686 us; speedup 1.0000x reference)
//
#include <hip/hip_runtime.h>
#include <hip/hip_bf16.h>
#include <math.h>

#define NMAX 200
#define EH 256
#define DH 512
#define NMIX 20
#define HE_BLK 131072   // 512*256
#define HD_BLK 262144   // 512*512

typedef unsigned short u16;
typedef __bf16 bfx8 __attribute__((ext_vector_type(8)));
typedef float  fx4  __attribute__((ext_vector_type(4)));
typedef u16    us8  __attribute__((ext_vector_type(8)));

#define MFMA16(a, b, c) __builtin_amdgcn_mfma_f32_16x16x32_bf16((a), (b), (c), 0, 0, 0)

__device__ __forceinline__ float sigm(float x) { return 1.0f / (1.0f + __expf(-x)); }
__device__ __forceinline__ u16 f2bf(float x) {
    unsigned u = __float_as_uint(x);
    unsigned r = u + 0x7fffu + ((u >> 16) & 1u);
    return (u16)(r >> 16);
}
__device__ __forceinline__ float bf2f(u16 h) { return __uint_as_float(((unsigned)h) << 16); }

// ---- token-flag sync: producer release-stores token; consumers poll relaxed then acquire once ----
__device__ __forceinline__ void poll_flags(int* f, int mask, int token) {
    const int idx = (threadIdx.x & 63) & mask;
    for (;;) {
        int v = __hip_atomic_load(&f[idx], __ATOMIC_RELAXED, __HIP_MEMORY_SCOPE_AGENT);
        if (__all(v >= token)) break;
        __builtin_amdgcn_s_sleep(4);
    }
    (void)__hip_atomic_load(&f[0], __ATOMIC_ACQUIRE, __HIP_MEMORY_SCOPE_AGENT);
}
__device__ __forceinline__ void release_flag(int* slot, int token) {
    __syncthreads();   // all waves' loads/stores drained (vmcnt) before release
    if (threadIdx.x == 0)
        __hip_atomic_store(slot, token, __ATOMIC_RELEASE, __HIP_MEMORY_SCOPE_AGENT);
}

// ---------------- prep: split fp32 weight [K][Nsrc] into transposed bf16 hi/lo [Nout][K] ----------------
__global__ __launch_bounds__(256) void prep_split_T(const float* __restrict__ src,
                                                    u16* dhi, u16* dlo, int K, int Nsrc, int Nout) {
    int idx = blockIdx.x * 256 + threadIdx.x;
    if (idx >= Nout * K) return;
    int n = idx / K, k = idx - n * K;
    float v = (n < Nsrc) ? src[k * Nsrc + n] : 0.0f;
    u16 hh = f2bf(v);
    dhi[idx] = hh;
    dlo[idx] = f2bf(v - bf2f(hh));
}

// ---------------- persistent encoder: B LDS-resident, A frags per-lane from global ----------------
// grid 256 = dir(2) x jx(8) x rt(16); group (dir,rt): 8 producers
__global__ __launch_bounds__(256, 1) void enc_persist(
    const float* __restrict__ x,
    const float* __restrict__ Wih_f, const float* __restrict__ b_f,
    const float* __restrict__ Wih_b, const float* __restrict__ b_b,
    const u16* __restrict__ whhT, u16* __restrict__ he, int* __restrict__ flags)
{
    extern __shared__ char smem[];
    u16* Bres = (u16*)smem;                 // [part][128][256] swizzled, 131072 B
    float* xL = (float*)(smem + 131072);    // [32][5]

    const int bx = blockIdx.x;
    const int dir = bx >> 7, jx = (bx >> 4) & 7, rt = bx & 15;
    const int j0 = jx * 32, row0 = rt * 32;
    int* ef = flags + (dir * 16 + rt) * 32;

    const float* Wih  = dir ? Wih_b : Wih_f;
    const float* bias = dir ? b_b : b_f;
    const u16* wTh = whhT + dir * 524288;
    const u16* wTl = wTh + 262144;

    const int tid = threadIdx.x;
    const int wv = tid >> 6, lane = tid & 63;
    const int mtr = (wv & 1) * 16, jh = wv >> 1;
    const int ln15 = lane & 15, kq = lane >> 4;
    const int j = jh * 16 + ln15;          // 0..31 within j-slice

    // B resident: n = g*32 + j, k granule-swizzled (g' = g ^ (n&7))
    for (int i = tid; i < 8192; i += 256) {
        int p = i >> 12, rem = i & 4095, n = rem >> 5, gs = rem & 31;
        const u16* wT = p ? wTl : wTh;
        int grow = (n >> 5) * 256 + j0 + (n & 31);
        *(us8*)&Bres[p * 32768 + n * 256 + gs * 8] =
            *(const us8*)&wT[grow * 256 + ((gs ^ (n & 7)) << 3)];
    }
    float wih[5][4], bi4[4];
#pragma unroll
    for (int g = 0; g < 4; ++g) {
        bi4[g] = bias[g * 256 + j0 + j];
#pragma unroll
        for (int i = 0; i < 5; ++i) wih[i][g] = Wih[i * 1024 + g * 256 + j0 + j];
    }
    float c4[4] = {0.f, 0.f, 0.f, 0.f};
    __syncthreads();

    for (int t = 0; t <= NMAX; ++t) {
        const int pb = t & 1, nb = pb ^ 1;
        const int ts = dir ? (NMAX - t) : t;
        const u16* hp_hi = he + ((pb * 2 + dir) * 2 + 0) * HE_BLK;
        const u16* hp_lo = he + ((pb * 2 + dir) * 2 + 1) * HE_BLK;
        u16* hn_hi = he + ((nb * 2 + dir) * 2 + 0) * HE_BLK;
        u16* hn_lo = he + ((nb * 2 + dir) * 2 + 1) * HE_BLK;

        if (tid < 160) xL[tid] = x[ts * 2560 + row0 * 5 + tid];
        if (t > 0) poll_flags(ef, 7, t);

        const u16* Ah = hp_hi + (row0 + mtr + ln15) * 256 + kq * 8;
        const u16* Al = hp_lo + (row0 + mtr + ln15) * 256 + kq * 8;
        fx4 acc[4] = {};
        bfx8 ah[2], al[2];
        ah[0] = *(const bfx8*)&Ah[0];
        al[0] = *(const bfx8*)&Al[0];
#pragma unroll
        for (int ch = 0; ch < 8; ++ch) {
            const int cur = ch & 1, nxt = cur ^ 1;
            if (ch < 7) {
                ah[nxt] = *(const bfx8*)&Ah[(ch + 1) * 32];
                al[nxt] = *(const bfx8*)&Al[(ch + 1) * 32];
            }
            const int kkg = ch * 4 + kq;
#pragma unroll
            for (int g = 0; g < 4; ++g) {
                const int n = g * 32 + j;
                const int ba = n * 256 + ((kkg ^ (n & 7)) << 3);
                bfx8 bh = *(const bfx8*)&Bres[ba];
                bfx8 bl = *(const bfx8*)&Bres[32768 + ba];
                acc[g] = MFMA16(ah[cur], bh, acc[g]);
                acc[g] = MFMA16(ah[cur], bl, acc[g]);
                acc[g] = MFMA16(al[cur], bh, acc[g]);
            }
        }
        __syncthreads();   // xL visible to all waves
#pragma unroll
        for (int r2 = 0; r2 < 4; ++r2) {
            const int rl = mtr + kq * 4 + r2;
            float gv[4];
#pragma unroll
            for (int g = 0; g < 4; ++g) {
                float s2 = acc[g][r2] + bi4[g];
#pragma unroll
                for (int i = 0; i < 5; ++i) s2 += xL[rl * 5 + i] * wih[i][g];
                gv[g] = s2;
            }
            float cv = c4[r2];
            cv = sigm(gv[1]) * cv + sigm(gv[0]) * tanhf(gv[2]);
            c4[r2] = cv;
            float hv = sigm(gv[3]) * tanhf(cv);
            const int gidx = (row0 + rl) * 256 + j0 + j;
            u16 hh = f2bf(hv);
            hn_hi[gidx] = hh;
            hn_lo[gidx] = f2bf(hv - bf2f(hh));
        }
        release_flag(&ef[jx], t + 1);
    }
}

// ---------------- latent 1: mean/logvar/z ----------------
__global__ __launch_bounds__(256) void latent1(
    const u16* he,
    const float* __restrict__ W_mu, const float* __restrict__ b_mu,
    const float* __restrict__ W_lv, const float* __restrict__ b_lv,
    const float* __restrict__ eps, float* z, float* out)
{
    __shared__ float hs[16 * 512];
    const int row0 = blockIdx.x * 16;
    const int tid = threadIdx.x;
    const u16* hf_hi = he + ((1 * 2 + 0) * 2 + 0) * HE_BLK;
    const u16* hf_lo = he + ((1 * 2 + 0) * 2 + 1) * HE_BLK;
    const u16* hb_hi = he + ((1 * 2 + 1) * 2 + 0) * HE_BLK;
    const u16* hb_lo = he + ((1 * 2 + 1) * 2 + 1) * HE_BLK;
    for (int i = tid; i < 8192; i += 256) {
        int r = i >> 9, col = i & 511;
        int gi = (row0 + r) * 256;
        float v;
        if (col < 256) v = bf2f(hf_hi[gi + col]) + bf2f(hf_lo[gi + col]);
        else { int cc = col - 256; v = bf2f(hb_hi[gi + cc]) + bf2f(hb_lo[gi + cc]); }
        hs[i] = v;
    }
    __syncthreads();
    for (int p = tid; p < 2048; p += 256) {
        int r = p >> 7, cc = p & 127;
        const float* hr = hs + r * 512;
        float m = 0, lv = 0;
#pragma unroll 8
        for (int k = 0; k < 512; ++k) {
            float hv = hr[k];
            m  += hv * W_mu[k * 128 + cc];
            lv += hv * W_lv[k * 128 + cc];
        }
        m += b_mu[cc]; lv += b_lv[cc];
        int b = row0 + r;
        out[512002 + b * 128 + cc] = m;
        out[577538 + b * 128 + cc] = lv;
        z[b * 128 + cc] = m + __expf(0.5f * lv) * eps[b * 128 + cc];
    }
}

// ---------------- latent 2: h0/c0; zpre = z@dec_Wih[5:] + dec_b ----------------
__global__ __launch_bounds__(256) void latent2(
    const float* __restrict__ z, const float* __restrict__ W_fc, const float* __restrict__ b_fc,
    const float* __restrict__ dWih, const float* __restrict__ dec_b,
    u16* hd, float* c_d, float* zpre)
{
    __shared__ float zs[16 * 128];
    const int row0 = blockIdx.y * 16;
    const int tid = threadIdx.x;
    u16* h0_hi = hd + 0;
    u16* h0_lo = hd + HD_BLK;
    {
        float4* dst = (float4*)zs;
        const float4* src = (const float4*)(z + row0 * 128);
        for (int i = tid; i < 512; i += 256) dst[i] = src[i];
    }
    __syncthreads();
    const int colbase = blockIdx.x * 128;
    for (int p = tid; p < 16 * 128; p += 256) {
        int r = p >> 7, cl = p & 127;
        int col = colbase + cl;
        const float* zr = zs + r * 128;
        int b = row0 + r;
        if (col < 1024) {
            float acc = 0;
#pragma unroll 8
            for (int k = 0; k < 128; ++k) acc += zr[k] * W_fc[k * 1024 + col];
            float v = tanhf(acc + b_fc[col]);
            if (col < 512) {
                u16 hh = f2bf(v);
                h0_hi[b * 512 + col] = hh;
                h0_lo[b * 512 + col] = f2bf(v - bf2f(hh));
            } else c_d[b * 512 + (col - 512)] = v;
        } else {
            int n = col - 1024;
            float acc = 0;
#pragma unroll 8
            for (int k = 0; k < 128; ++k) acc += zr[k] * dWih[(5 + k) * 2048 + n];
            zpre[b * 2048 + n] = acc + dec_b[n];
        }
    }
}

// ---------------- persistent decoder ----------------
// grid 256 = jx(32) x rt(8); rows 64/rt, j-slice 16; out-head on jx 24..31 (streamed W_out hi+lo frags)
__global__ __launch_bounds__(256, 1) void dec_persist(
    const float* __restrict__ x, const int* __restrict__ N_s,
    const float* __restrict__ dec_Wih, const float* __restrict__ b_out,
    const u16* __restrict__ decT, const u16* __restrict__ woutT,
    const float* __restrict__ zpre, const float* __restrict__ c_init,
    u16* __restrict__ hd, float* __restrict__ ybuf, float* __restrict__ out,
    int* __restrict__ flagsH, int* __restrict__ flagsY)
{
    extern __shared__ char smem[];
    u16* Bres  = (u16*)smem;                  // [part][64][512] swizzled, 131072 B
    float* xtL = (float*)(smem + 131072);     // 320
    float* sxs = xtL + 320;                   // 320
    int*  lenL = (int*)(sxs + 320);           // 64
    float* redL = (float*)(lenL + 64);        // 128

    const int bx = blockIdx.x;
    const int jx = bx >> 3, rt = bx & 7;
    const int j0 = jx * 16, row0 = rt * 64;
    const bool is_out = (jx >= 24);
    const int oj = jx - 24;
    int* hf = flagsH + rt * 32;
    int* yf = flagsY + rt * 32;

    const u16* wHh = decT;
    const u16* wHl = decT + 1048576;
    const u16* wOh = woutT;
    const u16* wOl = woutT + 65536;

    const int tid = threadIdx.x;
    const int wv = tid >> 6, lane = tid & 63;
    const int ln15 = lane & 15, kq = lane >> 4;
    const int mrb = wv * 16;     // wave rows [16wv,+16)

    for (int i = tid; i < 8192; i += 256) {
        int p = i >> 12, rem = i & 4095, n = rem >> 6, gs = rem & 63;
        const u16* wT = p ? wHl : wHh;
        int grow = (n >> 4) * 512 + j0 + (n & 15);
        *(us8*)&Bres[p * 32768 + n * 512 + gs * 8] =
            *(const us8*)&wT[grow * 512 + ((gs ^ (n & 7)) << 3)];
    }
    if (tid < 64) lenL[tid] = N_s[row0 + tid];
    for (int i = tid; i < 320; i += 256) sxs[i] = ((i % 5) == 2) ? 1.0f : 0.0f;

    float dw[5][4], zp[4][4], c4[4];
#pragma unroll
    for (int g = 0; g < 4; ++g)
#pragma unroll
        for (int i = 0; i < 5; ++i) dw[i][g] = dec_Wih[i * 2048 + g * 512 + j0 + ln15];
#pragma unroll
    for (int r2 = 0; r2 < 4; ++r2) {
        const int R = row0 + mrb + kq * 4 + r2;
        c4[r2] = c_init[R * 512 + j0 + ln15];
#pragma unroll
        for (int g = 0; g < 4; ++g) zp[r2][g] = zpre[R * 2048 + g * 512 + j0 + ln15];
    }
    __syncthreads();

    const int s_end = (is_out || jx == 0) ? 199 : 198;
    for (int s = 0; s <= s_end; ++s) {
        const bool do_cell = (s < 199);
        const bool do_y = (s > 0);
        const bool do_gemm = do_cell || is_out;
        const int pb = s & 1, nb = pb ^ 1;
        const u16* hp_hi = hd + (pb * 2 + 0) * HD_BLK;
        const u16* hp_lo = hd + (pb * 2 + 1) * HD_BLK;
        u16* hn_hi = hd + (nb * 2 + 0) * HD_BLK;
        u16* hn_lo = hd + (nb * 2 + 1) * HD_BLK;

        if (do_y) for (int i = tid; i < 320; i += 256) xtL[i] = x[s * 2560 + row0 * 5 + i];

        fx4 acc[4] = {};
        fx4 accy = {};
        if (do_gemm) {
            if (s > 0) poll_flags(hf, 31, s);
            const u16* Ah = hp_hi + (row0 + mrb + ln15) * 512 + kq * 8;
            const u16* Al = hp_lo + (row0 + mrb + ln15) * 512 + kq * 8;
            const u16* Ybh = wOh + (oj * 16 + ln15) * 512 + kq * 8;
            const u16* Ybl = wOl + (oj * 16 + ln15) * 512 + kq * 8;
            const bool use_y = is_out && do_y;
            bfx8 ah[2], al[2], ybh[2], ybl[2];
            ah[0] = *(const bfx8*)&Ah[0];
            al[0] = *(const bfx8*)&Al[0];
            if (use_y) { ybh[0] = *(const bfx8*)&Ybh[0]; ybl[0] = *(const bfx8*)&Ybl[0]; }
#pragma unroll
            for (int ch = 0; ch < 16; ++ch) {
                const int cur = ch & 1, nxt = cur ^ 1;
                if (ch < 15) {
                    ah[nxt] = *(const bfx8*)&Ah[(ch + 1) * 32];
                    al[nxt] = *(const bfx8*)&Al[(ch + 1) * 32];
                    if (use_y) {
                        ybh[nxt] = *(const bfx8*)&Ybh[(ch + 1) * 32];
                        ybl[nxt] = *(const bfx8*)&Ybl[(ch + 1) * 32];
                    }
                }
                const int kkg = ch * 4 + kq;
                if (do_cell) {
#pragma unroll
                    for (int g = 0; g < 4; ++g) {
                        const int n = g * 16 + ln15;
                        const int ba = n * 512 + ((kkg ^ (n & 7)) << 3);
                        bfx8 bh = *(const bfx8*)&Bres[ba];
                        bfx8 bl = *(const bfx8*)&Bres[32768 + ba];
                        acc[g] = MFMA16(ah[cur], bh, acc[g]);
                        acc[g] = MFMA16(ah[cur], bl, acc[g]);
                        acc[g] = MFMA16(al[cur], bh, acc[g]);
                    }
                }
                if (use_y) {
                    accy = MFMA16(ah[cur], ybh[cur], accy);
                    accy = MFMA16(ah[cur], ybl[cur], accy);   // restored A_hi * W_lo term (r4 bug: argmax flips)
                    accy = MFMA16(al[cur], ybh[cur], accy);
                }
            }
        }
        __syncthreads();   // xtL visible; prior-iter sxs reads complete

        if (do_y) {
            if (is_out) {
                const int col = oj * 16 + ln15;
#pragma unroll
                for (int r2 = 0; r2 < 4; ++r2) {
                    if (col < 123) {
                        const int R = row0 + mrb + kq * 4 + r2;
                        ybuf[R * 128 + col] = accy[r2] + b_out[col];
                    }
                }
                __syncthreads();
                if (tid == 0)
                    __hip_atomic_store(&yf[oj], s, __ATOMIC_RELEASE, __HIP_MEMORY_SCOPE_AGENT);
            }
            poll_flags(yf, 7, s);
            {
                const int row = tid >> 2, sub = tid & 3;
                const float* yr = ybuf + (row0 + row) * 128;
                const float dxv = xtL[row * 5], dyv = xtL[row * 5 + 1];
                float pm = -1e30f;
                for (int cg = sub; cg < NMIX; cg += 4) pm = fmaxf(pm, yr[cg * 6]);
                pm = fmaxf(pm, __shfl_xor(pm, 1));
                pm = fmaxf(pm, __shfl_xor(pm, 2));
                float S = 0, gp = 0, gx = 0, gy = 0;
                for (int cg = sub; cg < NMIX; cg += 4) {
                    float ph = yr[cg * 6], mux = yr[cg * 6 + 1], muy = yr[cg * 6 + 2];
                    float ssx = __expf(yr[cg * 6 + 3]), ssy = __expf(yr[cg * 6 + 4]);
                    float rho = tanhf(yr[cg * 6 + 5]);
                    float e = __expf(ph - pm);
                    float zx = (dxv - mux) / ssx, zy = (dyv - muy) / ssy;
                    float om = 1.0f - rho * rho;
                    float pdf = __expf(-(zx * zx + zy * zy - 2.0f * rho * zx * zy) / (2.0f * om))
                                * (0.15915494309189535f / (ssx * ssy * sqrtf(om)));
                    S += e; gp += e * pdf; gx += e * mux; gy += e * muy;
                }
#pragma unroll
                for (int off = 1; off < 4; off <<= 1) {
                    S += __shfl_xor(S, off); gp += __shfl_xor(gp, off);
                    gx += __shfl_xor(gx, off); gy += __shfl_xor(gy, off);
                }
                if (sub == 0) {
                    const int b = row0 + row;
                    float q0 = yr[120], q1 = yr[121], q2 = yr[122];
                    int len = lenL[row];
                    int am = 0; float bv = q0;
                    if (q1 > bv) { bv = q1; am = 1; }
                    if (q2 > bv) { bv = q2; am = 2; }
                    float s0, s1, s2, s3, s4;
                    if (s > len) { s0 = s1 = s2 = s3 = 0.0f; s4 = 1.0f; }
                    else { s0 = gx / S; s1 = gy / S; s2 = (am == 0); s3 = (am == 1); s4 = (am == 2); }
                    sxs[row * 5 + 0] = s0; sxs[row * 5 + 1] = s1; sxs[row * 5 + 2] = s2;
                    sxs[row * 5 + 3] = s3; sxs[row * 5 + 4] = s4;
                    if (jx == 0) {
                        float qm = fmaxf(q0, fmaxf(q1, q2));
                        float lse = qm + logf(__expf(q0 - qm) + __expf(q1 - qm) + __expf(q2 - qm));
                        float pl = -(xtL[row * 5 + 2] * (q0 - lse) + xtL[row * 5 + 3] * (q1 - lse)
                                     + xtL[row * 5 + 4] * (q2 - lse));
                        float ol = (s < len) ? -logf(gp / S + 1e-6f) : 0.0f;
                        float* so = out + (s - 1) * 2560 + b * 5;
                        so[0] = s0; so[1] = s1; so[2] = s2; so[3] = s3; so[4] = s4;
                        redL[row] = pl; redL[64 + row] = ol;
                    }
                }
            }
            __syncthreads();
            if (jx == 0 && tid == 0) {
                float spl = 0, sol = 0;
                for (int r = 0; r < 64; ++r) { spl += redL[r]; sol += redL[64 + r]; }
                atomicAdd(out + 512001, spl * (1.0f / 102400.0f));
                atomicAdd(out + 512000, sol * (1.0f / 102400.0f));
            }
        }

        if (do_cell) {
#pragma unroll
            for (int r2 = 0; r2 < 4; ++r2) {
                const int rl = mrb + kq * 4 + r2;
                float gv[4];
#pragma unroll
                for (int g = 0; g < 4; ++g) {
                    float sum = acc[g][r2] + zp[r2][g];
#pragma unroll
                    for (int i = 0; i < 5; ++i) sum += sxs[rl * 5 + i] * dw[i][g];
                    gv[g] = sum;
                }
                float cv = c4[r2];
                cv = sigm(gv[1]) * cv + sigm(gv[0]) * tanhf(gv[2]);
                c4[r2] = cv;
                float hv = sigm(gv[3]) * tanhf(cv);
                const int gidx = (row0 + rl) * 512 + j0 + ln15;
                u16 hh = f2bf(hv);
                hn_hi[gidx] = hh;
                hn_lo[gidx] = f2bf(hv - bf2f(hh));
            }
            release_flag(&hf[jx], s + 1);
        }
    }
}

extern "C" void kernel_launch(void* const* d_in, const int* in_sizes, int n_in,
                              void* d_out_, int out_size, void* d_ws, size_t ws_size,
                              hipStream_t stream) {
    const float* x         = (const float*)d_in[0];
    const int*   N_s       = (const int*)  d_in[1];
    const float* eps       = (const float*)d_in[2];
    const float* enc_Wih_f = (const float*)d_in[3];
    const float* enc_Whh_f = (const float*)d_in[4];
    const float* enc_b_f   = (const float*)d_in[5];
    const float* enc_Wih_b = (const float*)d_in[6];
    const float* enc_Whh_b = (const float*)d_in[7];
    const float* enc_b_b   = (const float*)d_in[8];
    const float* W_mu      = (const float*)d_in[9];
    const float* b_mu      = (const float*)d_in[10];
    const float* W_logvar  = (const float*)d_in[11];
    const float* b_logvar  = (const float*)d_in[12];
    const float* W_fc_in   = (const float*)d_in[13];
    const float* b_fc_in   = (const float*)d_in[14];
    const float* dec_Wih   = (const float*)d_in[15];
    const float* dec_Whh   = (const float*)d_in[16];
    const float* dec_b     = (const float*)d_in[17];
    const float* W_out     = (const float*)d_in[18];
    const float* b_out     = (const float*)d_in[19];
    float* out = (float*)d_out_;
    float* ws  = (float*)d_ws;

    float* c_d   = ws + 0;                     // 262144
    float* zpre  = ws + 262144;                // 1048576
    float* z     = ws + 1310720;               // 65536
    float* ybuf  = ws + 1376256;               // 65536
    int* flags   = (int*)(ws + 1441792);       // 1536 ints: enc 1024 | decH 256 | decY 256
    u16* U     = (u16*)(ws + 1443840);
    u16* he    = U;                   // 8 * 131072
    u16* hd    = U + 1048576;         // 4 * 262144
    u16* encT  = U + 2097152;         // 4 * 262144
    u16* decT  = U + 3145728;         // 2 * 1048576
    u16* woutT = U + 5242880;         // 2 * 65536

    hipMemsetAsync(he, 0, 4 * HE_BLK * sizeof(u16), stream);
    hipMemsetAsync(flags, 0, 1536 * sizeof(int), stream);
    hipMemsetAsync(out + 509440, 0, 2562 * sizeof(float), stream);

    prep_split_T<<<1024, 256, 0, stream>>>(enc_Whh_f, encT,           encT + 262144,  256, 1024, 1024);
    prep_split_T<<<1024, 256, 0, stream>>>(enc_Whh_b, encT + 524288,  encT + 786432,  256, 1024, 1024);
    prep_split_T<<<4096, 256, 0, stream>>>(dec_Whh,   decT,           decT + 1048576, 512, 2048, 2048);
    prep_split_T<<<256,  256, 0, stream>>>(W_out,     woutT,          woutT + 65536,  512, 123, 128);

    (void)hipFuncSetAttribute((const void*)enc_persist,
                              hipFuncAttributeMaxDynamicSharedMemorySize, 131712);
    (void)hipFuncSetAttribute((const void*)dec_persist,
                              hipFuncAttributeMaxDynamicSharedMemorySize, 134400);

    enc_persist<<<256, 256, 131712, stream>>>(x, enc_Wih_f, enc_b_f, enc_Wih_b, enc_b_b,
                                              encT, he, flags);
    latent1<<<32, 256, 0, stream>>>(he, W_mu, b_mu, W_logvar, b_logvar, eps, z, out);
    latent2<<<dim3(24, 32), 256, 0, stream>>>(z, W_fc_in, b_fc_in, dec_Wih, dec_b, hd, c_d, zpre);
    dec_persist<<<256, 256, 134400, stream>>>(x, N_s, dec_Wih, b_out, decT, woutT, zpre, c_d,
                                              hd, ybuf, out, flags + 1024, flags + 1280);
}

// Round 7
// 8190.574 us; speedup vs baseline: 1.3516x; 1.3516x over previous
//
#include <hip/hip_runtime.h>
#include <hip/hip_bf16.h>
#include <math.h>

#define NMIX 20

typedef unsigned short u16;
typedef unsigned int   u32;
typedef unsigned long long u64;
typedef __bf16 bfx8 __attribute__((ext_vector_type(8)));
typedef float  fx4  __attribute__((ext_vector_type(4)));
typedef u16    us8  __attribute__((ext_vector_type(8)));

#define MFMA16(a,b,c) __builtin_amdgcn_mfma_f32_16x16x32_bf16((a),(b),(c),0,0,0)

__device__ __forceinline__ float sigm(float x){ return 1.0f/(1.0f+__expf(-x)); }
__device__ __forceinline__ u16 f2bf(float x){ u32 u=__float_as_uint(x); return (u16)((u + 0x7fffu + ((u>>16)&1u))>>16); }
__device__ __forceinline__ float bf2f(u16 h){ return __uint_as_float(((u32)h)<<16); }
__device__ __forceinline__ u32 packh(float v){ u16 hh=f2bf(v); return ((u32)hh<<16) | (u32)f2bf(v - bf2f(hh)); }

__device__ __forceinline__ u64 ald64(const u64* p){ return __hip_atomic_load(p,__ATOMIC_RELAXED,__HIP_MEMORY_SCOPE_AGENT); }
__device__ __forceinline__ u32 ald32(const u32* p){ return __hip_atomic_load(p,__ATOMIC_RELAXED,__HIP_MEMORY_SCOPE_AGENT); }
__device__ __forceinline__ void ast64(u64* p,u64 v){ __hip_atomic_store(p,v,__ATOMIC_RELAXED,__HIP_MEMORY_SCOPE_AGENT); }
__device__ __forceinline__ void ast32(u32* p,u32 v){ __hip_atomic_store(p,v,__ATOMIC_RELAXED,__HIP_MEMORY_SCOPE_AGENT); }

// consumers: relaxed poll (sc1, serviced at LLC, NO cache-inv) + compiler fence
__device__ __forceinline__ void poll(const int* f,int mask,int tok){
  const int idx=(threadIdx.x&63)&mask;
  for(;;){ int v=__hip_atomic_load(f+idx,__ATOMIC_RELAXED,__HIP_MEMORY_SCOPE_AGENT);
    if(__all(v>=tok)) break; __builtin_amdgcn_s_sleep(2); }
  __atomic_signal_fence(__ATOMIC_SEQ_CST);
}

// ---------------- prep: split fp32 weight [K][Nsrc] -> transposed bf16 hi/lo [Nout][K] ----------------
__global__ __launch_bounds__(256) void prep_split_T(const float* __restrict__ src,
                                                    u16* dhi, u16* dlo, int K, int Nsrc, int Nout) {
    int idx = blockIdx.x * 256 + threadIdx.x;
    if (idx >= Nout * K) return;
    int n = idx / K, k = idx - n * K;
    float v = (n < Nsrc) ? src[k * Nsrc + n] : 0.0f;
    u16 hh = f2bf(v);
    dhi[idx] = hh;
    dlo[idx] = f2bf(v - bf2f(hh));
}

// ---------------- persistent encoder ----------------
// grid 64 = dir(2) x jx(4, 64 h-cols) x rt(8, 64 rows). N-split waves; B from L2; A chunk-staged LDS.
__global__ __launch_bounds__(256,1) void enc_persist(
    const float* __restrict__ x,
    const float* __restrict__ Wih_f, const float* __restrict__ b_f,
    const float* __restrict__ Wih_b, const float* __restrict__ b_b,
    const u16* __restrict__ encT, u32* __restrict__ he32, int* __restrict__ encF)
{
    __shared__ u16 AH[2*2048];
    __shared__ u16 AL[2*2048];
    __shared__ float xL[320];

    const int bx=blockIdx.x, dir=bx>>5, jx=(bx>>3)&3, rt=bx&7;
    const int j0=jx*64, row0=rt*64;
    int* ef = encF + (dir*8+rt)*32;
    const u16* wTh = encT + dir*524288;
    const u16* wTl = wTh + 262144;
    const float* Wih = dir? Wih_b : Wih_f;
    const float* bias= dir? b_b : b_f;

    const int tid=threadIdx.x, wv=tid>>6, lane=tid&63;
    const int ln15=lane&15, kq=lane>>4;
    const int jc = wv*16+ln15;
    const int prm = kq ^ ((ln15>>1)&3);
    const int arow = tid>>2, agran = tid&3, aprm = agran ^ ((arow>>1)&3);

    float wih[5][4], bi4[4];
#pragma unroll
    for(int g=0; g<4; ++g){
        bi4[g] = bias[g*256 + j0 + jc];
#pragma unroll
        for(int i=0;i<5;++i) wih[i][g] = Wih[i*1024 + g*256 + j0 + jc];
    }
    float c16[4][4] = {};

#pragma unroll 1
    for (int t=0; t<=200; ++t) {
      const int pb=t&1;
      const u32* hp = he32 + (pb*2+dir)*131072;
      u32* hn = he32 + ((pb^1)*2+dir)*131072;
      const int ts = dir ? 200-t : t;
      for (int i = tid; i < 320; i += 256) xL[i] = x[ts*2560 + row0*5 + i];   // FIX: was if(tid<320)
      poll(ef, 3, t);

      fx4 acc[4][4] = {};
      u64 q0[4], q1[4];
      auto LOADA=[&](int ch,u64*q){
        const u64* s=(const u64*)(hp+(size_t)(row0+arow)*256) + ch*16 + agran*4;
        q[0]=ald64(s); q[1]=ald64(s+1); q[2]=ald64(s+2); q[3]=ald64(s+3);
      };
      auto STAGEA=[&](int buf,const u64*q){
        us8 hv,lv;
#pragma unroll
        for(int i=0;i<4;++i){u32 pe=(u32)q[i],po=(u32)(q[i]>>32);
          hv[2*i]=(u16)(pe>>16); lv[2*i]=(u16)pe;
          hv[2*i+1]=(u16)(po>>16); lv[2*i+1]=(u16)po;}
        const int off=buf*2048 + arow*32 + aprm*8;
        *(us8*)&AH[off]=hv; *(us8*)&AL[off]=lv;
      };
      auto COMP=[&](int buf,int ch){
        bfx8 ah[4],al[4];
#pragma unroll
        for(int rta=0;rta<4;++rta){int off=buf*2048+(rta*16+ln15)*32+prm*8;
          ah[rta]=*(const bfx8*)&AH[off]; al[rta]=*(const bfx8*)&AL[off];}
#pragma unroll
        for(int nt=0;nt<4;++nt){
          size_t bo=(size_t)(nt*256 + j0 + jc)*256 + ch*32 + kq*8;
          bfx8 bh=*(const bfx8*)&wTh[bo], bl=*(const bfx8*)&wTl[bo];
#pragma unroll
          for(int rta=0;rta<4;++rta){
            acc[rta][nt]=MFMA16(ah[rta],bh,acc[rta][nt]);
            acc[rta][nt]=MFMA16(ah[rta],bl,acc[rta][nt]);
            acc[rta][nt]=MFMA16(al[rta],bh,acc[rta][nt]);}}
      };
      LOADA(0,q0); LOADA(1,q1); STAGEA(0,q0); __syncthreads();
#pragma unroll
      for(int ch=0; ch<8; ch+=2){
        if(ch+2<8) LOADA(ch+2,q0);
        STAGEA(1,q1);
        COMP(0,ch);
        __syncthreads();
        if(ch+3<8) LOADA(ch+3,q1);
        if(ch+2<8) STAGEA(0,q0);
        COMP(1,ch+1);
        __syncthreads();
      }
#pragma unroll
      for(int rta=0;rta<4;++rta)
#pragma unroll
      for(int r2=0;r2<4;++r2){
        const int rl=rta*16+kq*4+r2;
        float gv[4];
#pragma unroll
        for(int g=0;g<4;++g){
          float s2=acc[rta][g][r2]+bi4[g];
#pragma unroll
          for(int i=0;i<5;++i) s2+=xL[rl*5+i]*wih[i][g];
          gv[g]=s2;}
        float cv=c16[rta][r2];
        cv=sigm(gv[1])*cv+sigm(gv[0])*tanhf(gv[2]);
        c16[rta][r2]=cv;
        float hv2=sigm(gv[3])*tanhf(cv);
        ast32(&hn[(row0+rl)*256 + j0 + jc], packh(hv2));
      }
      __syncthreads();   // drains vmcnt (h stores acked at LLC) before flag
      if(tid==0) __hip_atomic_store(&ef[jx], t+1, __ATOMIC_RELAXED, __HIP_MEMORY_SCOPE_AGENT);
    }
}

// ---------------- latent 1: mean/logvar/z ----------------
__global__ __launch_bounds__(256) void latent1(
    const u32* __restrict__ he32,
    const float* __restrict__ W_mu, const float* __restrict__ b_mu,
    const float* __restrict__ W_lv, const float* __restrict__ b_lv,
    const float* __restrict__ eps, float* z, float* out)
{
    __shared__ float hs[16 * 512];
    const int row0 = blockIdx.x * 16;
    const int tid = threadIdx.x;
    const u32* hf = he32 + 2*131072;   // final buffer = buf1, dir0
    const u32* hb = he32 + 3*131072;   // buf1, dir1
    for (int i = tid; i < 8192; i += 256) {
        int r = i >> 9, col = i & 511;
        int gi = (row0 + r) * 256;
        u32 p = (col < 256) ? hf[gi + col] : hb[gi + (col - 256)];
        hs[i] = bf2f((u16)(p >> 16)) + bf2f((u16)p);
    }
    __syncthreads();
    for (int p = tid; p < 2048; p += 256) {
        int r = p >> 7, cc = p & 127;
        const float* hr = hs + r * 512;
        float m = 0, lv = 0;
#pragma unroll 8
        for (int k = 0; k < 512; ++k) {
            float hv = hr[k];
            m  += hv * W_mu[k * 128 + cc];
            lv += hv * W_lv[k * 128 + cc];
        }
        m += b_mu[cc]; lv += b_lv[cc];
        int b = row0 + r;
        out[512002 + b * 128 + cc] = m;
        out[577538 + b * 128 + cc] = lv;
        z[b * 128 + cc] = m + __expf(0.5f * lv) * eps[b * 128 + cc];
    }
}

// ---------------- latent 2: h0 (packed) / c0; zpre ----------------
__global__ __launch_bounds__(256) void latent2(
    const float* __restrict__ z, const float* __restrict__ W_fc, const float* __restrict__ b_fc,
    const float* __restrict__ dWih, const float* __restrict__ dec_b,
    u32* __restrict__ hd32, float* c_d, float* zpre)
{
    __shared__ float zs[16 * 128];
    const int row0 = blockIdx.y * 16;
    const int tid = threadIdx.x;
    {
        float4* dst = (float4*)zs;
        const float4* src = (const float4*)(z + row0 * 128);
        for (int i = tid; i < 512; i += 256) dst[i] = src[i];
    }
    __syncthreads();
    const int colbase = blockIdx.x * 128;
    for (int p = tid; p < 16 * 128; p += 256) {
        int r = p >> 7, cl = p & 127;
        int col = colbase + cl;
        const float* zr = zs + r * 128;
        int b = row0 + r;
        if (col < 1024) {
            float acc = 0;
#pragma unroll 8
            for (int k = 0; k < 128; ++k) acc += zr[k] * W_fc[k * 1024 + col];
            float v = tanhf(acc + b_fc[col]);
            if (col < 512) hd32[b * 512 + col] = packh(v);
            else           c_d[b * 512 + (col - 512)] = v;
        } else {
            int n = col - 1024;
            float acc = 0;
#pragma unroll 8
            for (int k = 0; k < 128; ++k) acc += zr[k] * dWih[(5 + k) * 2048 + n];
            zpre[b * 2048 + n] = acc + dec_b[n];
        }
    }
}

// ---------------- persistent decoder ----------------
// grid 72 = jx(9) x rt(8). jx<8: cell (64 rows x 64 h-cols); jx==8: out head + mixture + losses.
__global__ __launch_bounds__(256,1) void dec_persist(
    const float* __restrict__ x, const int* __restrict__ N_s,
    const float* __restrict__ dec_Wih, const float* __restrict__ b_out,
    const u16* __restrict__ decT, const u16* __restrict__ woutT,
    const float* __restrict__ zpre, const float* __restrict__ c_init,
    u32* __restrict__ hd32, float* __restrict__ sxsG, float* __restrict__ out,
    int* __restrict__ decHF, int* __restrict__ decSF)
{
    extern __shared__ char dsm[];
    u16*   AH   = (u16*)dsm;                  // [2][2048]
    u16*   AL   = AH + 4096;                  // [2][2048]
    float* sxsL = (float*)(dsm + 16384);      // [64][8]
    float* xtL  = (float*)(dsm + 18432);      // 320
    int*   lenL = (int*)(dsm + 19712);        // 64
    float* redL = (float*)(dsm + 19968);      // 128
    float* zpreL= (float*)(dsm + 20480);      // [64][258] (cell)
    float* yL   = (float*)(dsm + 20480);      // [64][132] (out)

    const int bx=blockIdx.x, jx=bx>>3, rt=bx&7;
    const int row0=rt*64;
    int* hF = decHF + rt*32;
    int* sF = decSF + rt*32;
    const u16* wHh = decT;
    const u16* wHl = decT + 1048576;
    const u16* wOh = woutT;
    const u16* wOl = woutT + 65536;

    const int tid=threadIdx.x, wv=tid>>6, lane=tid&63;
    const int ln15=lane&15, kq=lane>>4;
    const int jc = wv*16+ln15;
    const int prm = kq ^ ((ln15>>1)&3);
    const int arow = tid>>2, agran = tid&3, aprm = agran ^ ((arow>>1)&3);

    auto STAGEA=[&](const u32* hp, int ch, u64* q){
        const u64* s=(const u64*)(hp+(size_t)(row0+arow)*512) + ch*16 + agran*4;
        q[0]=ald64(s); q[1]=ald64(s+1); q[2]=ald64(s+2); q[3]=ald64(s+3);
    };
    auto WRITEA=[&](int buf,const u64*q){
        us8 hv,lv;
#pragma unroll
        for(int i=0;i<4;++i){u32 pe=(u32)q[i],po=(u32)(q[i]>>32);
          hv[2*i]=(u16)(pe>>16); lv[2*i]=(u16)pe;
          hv[2*i+1]=(u16)(po>>16); lv[2*i+1]=(u16)po;}
        const int off=buf*2048 + arow*32 + aprm*8;
        *(us8*)&AH[off]=hv; *(us8*)&AL[off]=lv;
    };

    if (jx < 8) {
        // ================= CELL =================
        const int j0 = jx*64;
        for (int i = tid; i < 16384; i += 256) {
            int r = i>>8, cc = i&255;
            zpreL[r*258+cc] = zpre[(size_t)(row0+r)*2048 + (cc>>6)*512 + j0 + (cc&63)];
        }
        for (int i = tid; i < 512; i += 256) sxsL[i] = ((i&7)==2) ? 1.0f : 0.0f;
        float dw[5][4], c16[4][4];
#pragma unroll
        for(int g=0;g<4;++g)
#pragma unroll
        for(int i=0;i<5;++i) dw[i][g] = dec_Wih[i*2048 + g*512 + j0 + jc];
#pragma unroll
        for(int rta=0;rta<4;++rta)
#pragma unroll
        for(int r2=0;r2<4;++r2)
            c16[rta][r2] = c_init[(size_t)(row0+rta*16+kq*4+r2)*512 + j0 + jc];
        __syncthreads();

#pragma unroll 1
        for (int s = 0; s < 199; ++s) {
            const int pb = s&1;
            const u32* hp = hd32 + pb*262144;
            u32* hn = hd32 + (pb^1)*262144;
            poll(hF, 7, s);

            fx4 acc[4][4] = {};
            u64 q0[4], q1[4];
            auto COMP=[&](int buf,int ch){
                bfx8 ah[4],al[4];
#pragma unroll
                for(int rta=0;rta<4;++rta){int off=buf*2048+(rta*16+ln15)*32+prm*8;
                  ah[rta]=*(const bfx8*)&AH[off]; al[rta]=*(const bfx8*)&AL[off];}
#pragma unroll
                for(int nt=0;nt<4;++nt){
                  size_t bo=(size_t)(nt*512 + j0 + jc)*512 + ch*32 + kq*8;
                  bfx8 bh=*(const bfx8*)&wHh[bo], bl=*(const bfx8*)&wHl[bo];
#pragma unroll
                  for(int rta=0;rta<4;++rta){
                    acc[rta][nt]=MFMA16(ah[rta],bh,acc[rta][nt]);
                    acc[rta][nt]=MFMA16(ah[rta],bl,acc[rta][nt]);
                    acc[rta][nt]=MFMA16(al[rta],bh,acc[rta][nt]);}}
            };
            STAGEA(hp,0,q0); STAGEA(hp,1,q1); WRITEA(0,q0); __syncthreads();
#pragma unroll
            for(int ch=0; ch<16; ch+=2){
                if(ch+2<16) STAGEA(hp,ch+2,q0);
                WRITEA(1,q1);
                COMP(0,ch);
                __syncthreads();
                if(ch+3<16) STAGEA(hp,ch+3,q1);
                if(ch+2<16) WRITEA(0,q0);
                COMP(1,ch+1);
                __syncthreads();
            }
            if (s > 0) {
                poll(sF, 0, s);
                if (tid < 64) {
                    const u64* p = (const u64*)sxsG + (rt*64 + tid)*4;
                    u64 v0 = ald64(p), v1 = ald64(p+1);
                    u32 v2 = ald32((const u32*)(p+2));
                    sxsL[tid*8+0] = __uint_as_float((u32)v0);
                    sxsL[tid*8+1] = __uint_as_float((u32)(v0>>32));
                    sxsL[tid*8+2] = __uint_as_float((u32)v1);
                    sxsL[tid*8+3] = __uint_as_float((u32)(v1>>32));
                    sxsL[tid*8+4] = __uint_as_float(v2);
                }
            }
            __syncthreads();
#pragma unroll
            for(int rta=0;rta<4;++rta)
#pragma unroll
            for(int r2=0;r2<4;++r2){
                const int rl=rta*16+kq*4+r2;
                float gv[4];
#pragma unroll
                for(int g=0;g<4;++g){
                    float s2=acc[rta][g][r2]+zpreL[rl*258 + g*64 + jc];
#pragma unroll
                    for(int i=0;i<5;++i) s2+=sxsL[rl*8+i]*dw[i][g];
                    gv[g]=s2;}
                float cv=c16[rta][r2];
                cv=sigm(gv[1])*cv+sigm(gv[0])*tanhf(gv[2]);
                c16[rta][r2]=cv;
                float hv2=sigm(gv[3])*tanhf(cv);
                ast32(&hn[(row0+rl)*512 + j0 + jc], packh(hv2));
            }
            __syncthreads();
            if(tid==0) __hip_atomic_store(&hF[jx], s+1, __ATOMIC_RELAXED, __HIP_MEMORY_SCOPE_AGENT);
        }
    } else {
        // ================= OUT HEAD =================
        if (tid < 64) lenL[tid] = N_s[row0 + tid];
        float bo2[2];
#pragma unroll
        for(int nt=0;nt<2;++nt){ int col=wv*32+nt*16+ln15; bo2[nt] = (col<123)? b_out[col] : 0.0f; }
        __syncthreads();

#pragma unroll 1
        for (int s = 1; s < 200; ++s) {
            const int pb = s&1;
            const u32* hp = hd32 + pb*262144;
            for (int i = tid; i < 320; i += 256) xtL[i] = x[s*2560 + row0*5 + i];   // FIX: was if(tid<320)
            poll(hF, 7, s);

            fx4 acc[4][2] = {};
            u64 q0[4], q1[4];
            auto COMP=[&](int buf,int ch){
                bfx8 ah[4],al[4];
#pragma unroll
                for(int rta=0;rta<4;++rta){int off=buf*2048+(rta*16+ln15)*32+prm*8;
                  ah[rta]=*(const bfx8*)&AH[off]; al[rta]=*(const bfx8*)&AL[off];}
#pragma unroll
                for(int nt=0;nt<2;++nt){
                  size_t bo=(size_t)(wv*32 + nt*16 + ln15)*512 + ch*32 + kq*8;
                  bfx8 bh=*(const bfx8*)&wOh[bo], bl=*(const bfx8*)&wOl[bo];
#pragma unroll
                  for(int rta=0;rta<4;++rta){
                    acc[rta][nt]=MFMA16(ah[rta],bh,acc[rta][nt]);
                    acc[rta][nt]=MFMA16(ah[rta],bl,acc[rta][nt]);
                    acc[rta][nt]=MFMA16(al[rta],bh,acc[rta][nt]);}}
            };
            STAGEA(hp,0,q0); STAGEA(hp,1,q1); WRITEA(0,q0); __syncthreads();
#pragma unroll
            for(int ch=0; ch<16; ch+=2){
                if(ch+2<16) STAGEA(hp,ch+2,q0);
                WRITEA(1,q1);
                COMP(0,ch);
                __syncthreads();
                if(ch+3<16) STAGEA(hp,ch+3,q1);
                if(ch+2<16) WRITEA(0,q0);
                COMP(1,ch+1);
                __syncthreads();
            }
#pragma unroll
            for(int rta=0;rta<4;++rta)
#pragma unroll
            for(int nt=0;nt<2;++nt)
#pragma unroll
            for(int r2=0;r2<4;++r2)
                yL[(rta*16+kq*4+r2)*132 + wv*32+nt*16+ln15] = acc[rta][nt][r2] + bo2[nt];
            __syncthreads();
            {
                const int row = tid>>2, sub = tid&3;
                const float* yr = &yL[row*132];
                const float dxv = xtL[row*5], dyv = xtL[row*5+1];
                float pm = -1e30f;
                for (int cg = sub; cg < NMIX; cg += 4) pm = fmaxf(pm, yr[cg*6]);
                pm = fmaxf(pm, __shfl_xor(pm, 1));
                pm = fmaxf(pm, __shfl_xor(pm, 2));
                float S = 0, gp = 0, gx = 0, gy = 0;
                for (int cg = sub; cg < NMIX; cg += 4) {
                    float ph = yr[cg*6], mux = yr[cg*6+1], muy = yr[cg*6+2];
                    float ssx = __expf(yr[cg*6+3]), ssy = __expf(yr[cg*6+4]);
                    float rho = tanhf(yr[cg*6+5]);
                    float e = __expf(ph - pm);
                    float zx = (dxv - mux)/ssx, zy = (dyv - muy)/ssy;
                    float om = 1.0f - rho*rho;
                    float pdf = __expf(-(zx*zx + zy*zy - 2.0f*rho*zx*zy)/(2.0f*om))
                                * (0.15915494309189535f/(ssx*ssy*sqrtf(om)));
                    S += e; gp += e*pdf; gx += e*mux; gy += e*muy;
                }
#pragma unroll
                for (int off = 1; off < 4; off <<= 1) {
                    S += __shfl_xor(S, off); gp += __shfl_xor(gp, off);
                    gx += __shfl_xor(gx, off); gy += __shfl_xor(gy, off);
                }
                if (sub == 0) {
                    const int b = row0 + row;
                    float q0v = yr[120], q1v = yr[121], q2v = yr[122];
                    int len = lenL[row];
                    int am = 0; float bv = q0v;
                    if (q1v > bv) { bv = q1v; am = 1; }
                    if (q2v > bv) { bv = q2v; am = 2; }
                    float s0,s1,s2,s3,s4;
                    if (s > len) { s0=s1=s2=s3=0.0f; s4=1.0f; }
                    else { s0=gx/S; s1=gy/S; s2=(am==0); s3=(am==1); s4=(am==2); }
                    u64* p = (u64*)sxsG + (rt*64+row)*4;
                    ast64(p,   (u64)__float_as_uint(s0) | ((u64)__float_as_uint(s1)<<32));
                    ast64(p+1, (u64)__float_as_uint(s2) | ((u64)__float_as_uint(s3)<<32));
                    ast32(((u32*)p)+4, __float_as_uint(s4));
                    float qm = fmaxf(q0v, fmaxf(q1v, q2v));
                    float lse = qm + logf(__expf(q0v-qm)+__expf(q1v-qm)+__expf(q2v-qm));
                    float pl = -(xtL[row*5+2]*(q0v-lse) + xtL[row*5+3]*(q1v-lse) + xtL[row*5+4]*(q2v-lse));
                    float ol = (s < len) ? -logf(gp/S + 1e-6f) : 0.0f;
                    float* so = out + (s-1)*2560 + b*5;
                    so[0]=s0; so[1]=s1; so[2]=s2; so[3]=s3; so[4]=s4;
                    redL[row] = pl; redL[64+row] = ol;
                }
            }
            __syncthreads();
            if (tid == 0) {
                float spl=0, sol=0;
                for (int r=0;r<64;++r){ spl+=redL[r]; sol+=redL[64+r]; }
                atomicAdd(out + 512001, spl * (1.0f/102400.0f));
                atomicAdd(out + 512000, sol * (1.0f/102400.0f));
                __hip_atomic_store(&sF[0], s, __ATOMIC_RELAXED, __HIP_MEMORY_SCOPE_AGENT);
            }
        }
    }
}

extern "C" void kernel_launch(void* const* d_in, const int* in_sizes, int n_in,
                              void* d_out_, int out_size, void* d_ws, size_t ws_size,
                              hipStream_t stream) {
    const float* x         = (const float*)d_in[0];
    const int*   N_s       = (const int*)  d_in[1];
    const float* eps       = (const float*)d_in[2];
    const float* enc_Wih_f = (const float*)d_in[3];
    const float* enc_Whh_f = (const float*)d_in[4];
    const float* enc_b_f   = (const float*)d_in[5];
    const float* enc_Wih_b = (const float*)d_in[6];
    const float* enc_Whh_b = (const float*)d_in[7];
    const float* enc_b_b   = (const float*)d_in[8];
    const float* W_mu      = (const float*)d_in[9];
    const float* b_mu      = (const float*)d_in[10];
    const float* W_logvar  = (const float*)d_in[11];
    const float* b_logvar  = (const float*)d_in[12];
    const float* W_fc_in   = (const float*)d_in[13];
    const float* b_fc_in   = (const float*)d_in[14];
    const float* dec_Wih   = (const float*)d_in[15];
    const float* dec_Whh   = (const float*)d_in[16];
    const float* dec_b     = (const float*)d_in[17];
    const float* W_out     = (const float*)d_in[18];
    const float* b_out     = (const float*)d_in[19];
    float* out = (float*)d_out_;
    float* ws  = (float*)d_ws;

    float* c_d   = ws + 0;                      // 262144
    float* zpre  = ws + 262144;                 // 1048576
    float* z     = ws + 1310720;                // 65536
    float* sxsG  = ws + 1376256;                // 4096 (8rt x 64rows x 8)
    int*   flags = (int*)(ws + 1380352);        // 1024: encF 512 | decHF 256 | decSF 256
    u32*   hd32  = (u32*)(ws + 1381376);        // 2 x 262144
    u32*   he32  = (u32*)(ws + 1905664);        // 4 x 131072 (buf x dir)
    u16*   encT  = (u16*)(ws + 2429952);        // 4 x 262144 u16
    u16*   decT  = (u16*)(ws + 2954240);        // 2 x 1048576 u16
    u16*   woutT = (u16*)(ws + 4002816);        // 2 x 65536 u16
    int* encF  = flags;
    int* decHF = flags + 512;
    int* decSF = flags + 768;

    hipMemsetAsync(he32, 0, 262144 * sizeof(u32), stream);         // h(0) both dirs, buf0
    hipMemsetAsync(flags, 0, 1024 * sizeof(int), stream);
    hipMemsetAsync(out + 509440, 0, 2562 * sizeof(float), stream); // stroke row 199 + losses

    prep_split_T<<<1024, 256, 0, stream>>>(enc_Whh_f, encT,          encT + 262144,  256, 1024, 1024);
    prep_split_T<<<1024, 256, 0, stream>>>(enc_Whh_b, encT + 524288, encT + 786432,  256, 1024, 1024);
    prep_split_T<<<4096, 256, 0, stream>>>(dec_Whh,   decT,          decT + 1048576, 512, 2048, 2048);
    prep_split_T<<<256,  256, 0, stream>>>(W_out,     woutT,         woutT + 65536,  512, 123, 128);

    (void)hipFuncSetAttribute((const void*)dec_persist,
                              hipFuncAttributeMaxDynamicSharedMemorySize, 87040);

    enc_persist<<<64, 256, 0, stream>>>(x, enc_Wih_f, enc_b_f, enc_Wih_b, enc_b_b, encT, he32, encF);
    latent1<<<32, 256, 0, stream>>>(he32, W_mu, b_mu, W_logvar, b_logvar, eps, z, out);
    latent2<<<dim3(24, 32), 256, 0, stream>>>(z, W_fc_in, b_fc_in, dec_Wih, dec_b, hd32, c_d, zpre);
    dec_persist<<<72, 256, 86528, stream>>>(x, N_s, dec_Wih, b_out, decT, woutT, zpre, c_d,
                                            hd32, sxsG, out, decHF, decSF);
}

// Round 8
// 7143.591 us; speedup vs baseline: 1.5497x; 1.1466x over previous
//
#include <hip/hip_runtime.h>
#include <hip/hip_bf16.h>
#include <math.h>

#define NMIX 20

typedef unsigned short u16;
typedef unsigned int   u32;
typedef unsigned long long u64;
typedef __bf16 bfx8 __attribute__((ext_vector_type(8)));
typedef float  fx4  __attribute__((ext_vector_type(4)));

#define MFMA16(a,b,c) __builtin_amdgcn_mfma_f32_16x16x32_bf16((a),(b),(c),0,0,0)

__device__ __forceinline__ float sigm(float x){ return 1.0f/(1.0f+__expf(-x)); }
__device__ __forceinline__ u16 f2bf(float x){ u32 u=__float_as_uint(x); return (u16)((u + 0x7fffu + ((u>>16)&1u))>>16); }
__device__ __forceinline__ float bf2f(u16 h){ return __uint_as_float(((u32)h)<<16); }
__device__ __forceinline__ u32 packh(float v){ u16 hh=f2bf(v); return ((u32)hh<<16) | (u32)f2bf(v - bf2f(hh)); }

__device__ __forceinline__ u64 ald64(const u64* p){ return __hip_atomic_load(p,__ATOMIC_RELAXED,__HIP_MEMORY_SCOPE_AGENT); }
__device__ __forceinline__ u32 ald32(const u32* p){ return __hip_atomic_load(p,__ATOMIC_RELAXED,__HIP_MEMORY_SCOPE_AGENT); }
__device__ __forceinline__ void ast64(u64* p,u64 v){ __hip_atomic_store(p,v,__ATOMIC_RELAXED,__HIP_MEMORY_SCOPE_AGENT); }
__device__ __forceinline__ void ast32(u32* p,u32 v){ __hip_atomic_store(p,v,__ATOMIC_RELAXED,__HIP_MEMORY_SCOPE_AGENT); }

// consumers: relaxed poll (serviced coherently at LLC, no cache maintenance) + compiler fence
__device__ __forceinline__ void poll(const int* f,int mask,int tok){
  const int idx=(threadIdx.x&63)&mask;
  for(;;){ int v=__hip_atomic_load(f+idx,__ATOMIC_RELAXED,__HIP_MEMORY_SCOPE_AGENT);
    if(__all(v>=tok)) break; __builtin_amdgcn_s_sleep(1); }
  __atomic_signal_fence(__ATOMIC_SEQ_CST);
}

// ---------------- prep: split fp32 weight [K][Nsrc] -> transposed bf16 hi/lo [Nout][K] ----------------
__global__ __launch_bounds__(256) void prep_split_T(const float* __restrict__ src,
                                                    u16* dhi, u16* dlo, int K, int Nsrc, int Nout) {
    int idx = blockIdx.x * 256 + threadIdx.x;
    if (idx >= Nout * K) return;
    int n = idx / K, k = idx - n * K;
    float v = (n < Nsrc) ? src[k * Nsrc + n] : 0.0f;
    u16 hh = f2bf(v);
    dhi[idx] = hh;
    dlo[idx] = f2bf(v - bf2f(hh));
}

// ---------------- persistent encoder ----------------
// grid 128 = dir(2) x jx(4, 64 h-cols) x rt(16, 32 rows). Batched far-load A staging.
__global__ __launch_bounds__(256,1) void enc_persist(
    const float* __restrict__ x,
    const float* __restrict__ Wih_f, const float* __restrict__ b_f,
    const float* __restrict__ Wih_b, const float* __restrict__ b_b,
    const u16* __restrict__ encT, u32* __restrict__ he32, int* __restrict__ encF)
{
    __shared__ u16 AH[32*256];    // 16KB, full K
    __shared__ u16 AL[32*256];    // 16KB
    __shared__ float xL[160];

    const int bx=blockIdx.x, dir=bx>>6, jx=(bx>>4)&3, rt=bx&15;
    const int j0=jx*64, row0=rt*32;
    int* ef = encF + (dir*16+rt)*32;
    const u16* wTh = encT + dir*524288;
    const u16* wTl = wTh + 262144;
    const float* Wih = dir? Wih_b : Wih_f;
    const float* bias= dir? b_b : b_f;

    const int tid=threadIdx.x, wv=tid>>6, lane=tid&63;
    const int ln15=lane&15, kq=lane>>4;
    const int jc = wv*16+ln15;
    const int arow = tid>>3, agran = tid&7;

    float wih[5][4], bi4[4];
#pragma unroll
    for(int g=0; g<4; ++g){
        bi4[g] = bias[g*256 + j0 + jc];
#pragma unroll
        for(int i=0;i<5;++i) wih[i][g] = Wih[i*1024 + g*256 + j0 + jc];
    }
    float c16[2][4] = {};

#pragma unroll 1
    for (int t=0; t<=200; ++t) {
      const int pb=t&1;
      const u32* hp = he32 + (pb*2+dir)*131072;
      u32* hn = he32 + ((pb^1)*2+dir)*131072;
      const int ts = dir ? 200-t : t;
      for (int i = tid; i < 160; i += 256) xL[i] = x[ts*2560 + row0*5 + i];
      poll(ef, 3, t);

      // batch: 16 coherent u64 loads per thread (whole K)
      u64 q[16];
      {
        const u64* s = (const u64*)(hp + (size_t)(row0+arow)*256);
#pragma unroll
        for(int i=0;i<16;++i) q[i] = ald64(s + i*8 + agran);
      }
#pragma unroll
      for(int i=0;i<16;++i){
        u32 pe=(u32)q[i], po=(u32)(q[i]>>32);
        int ui = i*8 + agran;
        int off = arow*256 + (((ui>>2) ^ (arow&7))<<3) + (ui&3)*2;
        *(u32*)&AH[off] = (pe>>16) | (po & 0xffff0000u);
        *(u32*)&AL[off] = (pe & 0xffffu) | (po<<16);
      }
      __syncthreads();

      fx4 acc[2][4] = {};
#pragma unroll
      for(int ch=0; ch<8; ++ch){
        bfx8 ah[2], al[2];
#pragma unroll
        for(int rta=0;rta<2;++rta){
          int off = (rta*16+ln15)*256 + (((ch*4+kq)^(ln15&7))<<3);
          ah[rta]=*(const bfx8*)&AH[off]; al[rta]=*(const bfx8*)&AL[off];
        }
#pragma unroll
        for(int nt=0;nt<4;++nt){
          size_t bo=(size_t)(nt*256 + j0 + jc)*256 + ch*32 + kq*8;
          bfx8 bh=*(const bfx8*)&wTh[bo], bl=*(const bfx8*)&wTl[bo];
#pragma unroll
          for(int rta=0;rta<2;++rta){
            acc[rta][nt]=MFMA16(ah[rta],bh,acc[rta][nt]);
            acc[rta][nt]=MFMA16(ah[rta],bl,acc[rta][nt]);
            acc[rta][nt]=MFMA16(al[rta],bh,acc[rta][nt]);}}
      }
#pragma unroll
      for(int rta=0;rta<2;++rta)
#pragma unroll
      for(int r2=0;r2<4;++r2){
        const int rl=rta*16+kq*4+r2;
        float gv[4];
#pragma unroll
        for(int g=0;g<4;++g){
          float s2=acc[rta][g][r2]+bi4[g];
#pragma unroll
          for(int i=0;i<5;++i) s2+=xL[rl*5+i]*wih[i][g];
          gv[g]=s2;}
        float cv=c16[rta][r2];
        cv=sigm(gv[1])*cv+sigm(gv[0])*tanhf(gv[2]);
        c16[rta][r2]=cv;
        float hv2=sigm(gv[3])*tanhf(cv);
        ast32(&hn[(row0+rl)*256 + j0 + jc], packh(hv2));
      }
      __syncthreads();   // drains vmcnt (h stores acked) before flag; also guards AH/AL reuse
      if(tid==0) __hip_atomic_store(&ef[jx], t+1, __ATOMIC_RELAXED, __HIP_MEMORY_SCOPE_AGENT);
    }
}

// ---------------- latent 1: mean/logvar/z ----------------
__global__ __launch_bounds__(256) void latent1(
    const u32* __restrict__ he32,
    const float* __restrict__ W_mu, const float* __restrict__ b_mu,
    const float* __restrict__ W_lv, const float* __restrict__ b_lv,
    const float* __restrict__ eps, float* z, float* out)
{
    __shared__ float hs[16 * 512];
    const int row0 = blockIdx.x * 16;
    const int tid = threadIdx.x;
    const u32* hf = he32 + 2*131072;   // final buffer = buf1, dir0
    const u32* hb = he32 + 3*131072;   // buf1, dir1
    for (int i = tid; i < 8192; i += 256) {
        int r = i >> 9, col = i & 511;
        int gi = (row0 + r) * 256;
        u32 p = (col < 256) ? hf[gi + col] : hb[gi + (col - 256)];
        hs[i] = bf2f((u16)(p >> 16)) + bf2f((u16)p);
    }
    __syncthreads();
    for (int p = tid; p < 2048; p += 256) {
        int r = p >> 7, cc = p & 127;
        const float* hr = hs + r * 512;
        float m = 0, lv = 0;
#pragma unroll 8
        for (int k = 0; k < 512; ++k) {
            float hv = hr[k];
            m  += hv * W_mu[k * 128 + cc];
            lv += hv * W_lv[k * 128 + cc];
        }
        m += b_mu[cc]; lv += b_lv[cc];
        int b = row0 + r;
        out[512002 + b * 128 + cc] = m;
        out[577538 + b * 128 + cc] = lv;
        z[b * 128 + cc] = m + __expf(0.5f * lv) * eps[b * 128 + cc];
    }
}

// ---------------- latent 2: h0 (packed) / c0; zpre ----------------
__global__ __launch_bounds__(256) void latent2(
    const float* __restrict__ z, const float* __restrict__ W_fc, const float* __restrict__ b_fc,
    const float* __restrict__ dWih, const float* __restrict__ dec_b,
    u32* __restrict__ hd32, float* c_d, float* zpre)
{
    __shared__ float zs[16 * 128];
    const int row0 = blockIdx.y * 16;
    const int tid = threadIdx.x;
    {
        float4* dst = (float4*)zs;
        const float4* src = (const float4*)(z + row0 * 128);
        for (int i = tid; i < 512; i += 256) dst[i] = src[i];
    }
    __syncthreads();
    const int colbase = blockIdx.x * 128;
    for (int p = tid; p < 16 * 128; p += 256) {
        int r = p >> 7, cl = p & 127;
        int col = colbase + cl;
        const float* zr = zs + r * 128;
        int b = row0 + r;
        if (col < 1024) {
            float acc = 0;
#pragma unroll 8
            for (int k = 0; k < 128; ++k) acc += zr[k] * W_fc[k * 1024 + col];
            float v = tanhf(acc + b_fc[col]);
            if (col < 512) hd32[b * 512 + col] = packh(v);
            else           c_d[b * 512 + (col - 512)] = v;
        } else {
            int n = col - 1024;
            float acc = 0;
#pragma unroll 8
            for (int k = 0; k < 128; ++k) acc += zr[k] * dWih[(5 + k) * 2048 + n];
            zpre[b * 2048 + n] = acc + dec_b[n];
        }
    }
}

// ---------------- persistent decoder ----------------
// grid 144 = jx(9) x rt(16, 32 rows). jx<8: cell (64 h-cols); jx==8: out head for its rt.
__global__ __launch_bounds__(256,1) void dec_persist(
    const float* __restrict__ x, const int* __restrict__ N_s,
    const float* __restrict__ dec_Wih, const float* __restrict__ b_out,
    const u16* __restrict__ decT, const u16* __restrict__ woutT,
    const float* __restrict__ zpre, const float* __restrict__ c_init,
    u32* __restrict__ hd32, float* __restrict__ sxsG, float* __restrict__ out,
    int* __restrict__ decHF, int* __restrict__ decSF)
{
    __shared__ u16 AH[32*256];        // 16KB, half-K batch
    __shared__ u16 AL[32*256];        // 16KB
    __shared__ float sxsL[32*8];
    __shared__ float xtL[160];
    __shared__ float yL[32*132];      // out-head only
    __shared__ int  lenL[32];
    __shared__ float redL[64];

    const int bx=blockIdx.x, jx=bx>>4, rt=bx&15;
    const int row0=rt*32;
    int* hF = decHF + rt*32;
    int* sF = decSF + rt*32;
    const u16* wHh = decT;
    const u16* wHl = decT + 1048576;
    const u16* wOh = woutT;
    const u16* wOl = woutT + 65536;

    const int tid=threadIdx.x, wv=tid>>6, lane=tid&63;
    const int ln15=lane&15, kq=lane>>4;
    const int jc = wv*16+ln15;
    const int arow = tid>>3, agran = tid&7;

    auto LOADA=[&](const u32* hp, int b, u64* q){
        const u64* s = (const u64*)(hp + (size_t)(row0+arow)*512 + b*256);
#pragma unroll
        for(int i=0;i<16;++i) q[i] = ald64(s + i*8 + agran);
    };
    auto WRITEA=[&](const u64* q){
#pragma unroll
        for(int i=0;i<16;++i){
            u32 pe=(u32)q[i], po=(u32)(q[i]>>32);
            int ui = i*8 + agran;
            int off = arow*256 + (((ui>>2) ^ (arow&7))<<3) + (ui&3)*2;
            *(u32*)&AH[off] = (pe>>16) | (po & 0xffff0000u);
            *(u32*)&AL[off] = (pe & 0xffffu) | (po<<16);
        }
    };

    if (jx < 8) {
        // ================= CELL: 32 rows x 64 h-cols, K=512 =================
        const int j0 = jx*64;
        float dw[5][4], zp[2][4][4], c16[2][4];
#pragma unroll
        for(int g=0;g<4;++g)
#pragma unroll
        for(int i=0;i<5;++i) dw[i][g] = dec_Wih[i*2048 + g*512 + j0 + jc];
#pragma unroll
        for(int rta=0;rta<2;++rta)
#pragma unroll
        for(int r2=0;r2<4;++r2){
            const int R = row0 + rta*16 + kq*4 + r2;
            c16[rta][r2] = c_init[(size_t)R*512 + j0 + jc];
#pragma unroll
            for(int g=0;g<4;++g) zp[rta][r2][g] = zpre[(size_t)R*2048 + g*512 + j0 + jc];
        }
        for (int i = tid; i < 256; i += 256) sxsL[i] = ((i&7)==2) ? 1.0f : 0.0f;
        __syncthreads();

#pragma unroll 1
        for (int s = 0; s < 199; ++s) {
            const u32* hp = hd32 + (s&1)*262144;
            u32* hn = hd32 + ((s&1)^1)*262144;
            poll(hF, 7, s);

            fx4 acc[2][4] = {};
            u64 q[16], q2[16];
            LOADA(hp,0,q);
            WRITEA(q); __syncthreads();
            LOADA(hp,1,q2);                        // batch-1 in flight under batch-0 compute
#pragma unroll
            for(int b=0;b<2;++b){
                if(b){ __syncthreads(); WRITEA(q2); __syncthreads(); }
#pragma unroll
                for(int ch=0; ch<8; ++ch){
                    bfx8 ah[2], al[2];
#pragma unroll
                    for(int rta=0;rta<2;++rta){
                        int off = (rta*16+ln15)*256 + (((ch*4+kq)^(ln15&7))<<3);
                        ah[rta]=*(const bfx8*)&AH[off]; al[rta]=*(const bfx8*)&AL[off];
                    }
#pragma unroll
                    for(int nt=0;nt<4;++nt){
                        size_t bo=(size_t)(nt*512 + j0 + jc)*512 + b*256 + ch*32 + kq*8;
                        bfx8 bh=*(const bfx8*)&wHh[bo], bl=*(const bfx8*)&wHl[bo];
#pragma unroll
                        for(int rta=0;rta<2;++rta){
                            acc[rta][nt]=MFMA16(ah[rta],bh,acc[rta][nt]);
                            acc[rta][nt]=MFMA16(ah[rta],bl,acc[rta][nt]);
                            acc[rta][nt]=MFMA16(al[rta],bh,acc[rta][nt]);}}
                }
            }
            if (s > 0) {
                poll(sF, 0, s);
                if (tid < 32) {
                    const u64* p = (const u64*)sxsG + (rt*32 + tid)*4;
                    u64 v0 = ald64(p), v1 = ald64(p+1);
                    u32 v2 = ald32((const u32*)(p+2));
                    sxsL[tid*8+0] = __uint_as_float((u32)v0);
                    sxsL[tid*8+1] = __uint_as_float((u32)(v0>>32));
                    sxsL[tid*8+2] = __uint_as_float((u32)v1);
                    sxsL[tid*8+3] = __uint_as_float((u32)(v1>>32));
                    sxsL[tid*8+4] = __uint_as_float(v2);
                }
            }
            __syncthreads();
#pragma unroll
            for(int rta=0;rta<2;++rta)
#pragma unroll
            for(int r2=0;r2<4;++r2){
                const int rl=rta*16+kq*4+r2;
                float gv[4];
#pragma unroll
                for(int g=0;g<4;++g){
                    float s2=acc[rta][g][r2]+zp[rta][r2][g];
#pragma unroll
                    for(int i=0;i<5;++i) s2+=sxsL[rl*8+i]*dw[i][g];
                    gv[g]=s2;}
                float cv=c16[rta][r2];
                cv=sigm(gv[1])*cv+sigm(gv[0])*tanhf(gv[2]);
                c16[rta][r2]=cv;
                float hv2=sigm(gv[3])*tanhf(cv);
                ast32(&hn[(size_t)(row0+rl)*512 + j0 + jc], packh(hv2));
            }
            __syncthreads();
            if(tid==0) __hip_atomic_store(&hF[jx], s+1, __ATOMIC_RELAXED, __HIP_MEMORY_SCOPE_AGENT);
        }
    } else {
        // ================= OUT HEAD: 32 rows x 123 cols, K=512 =================
        if (tid < 32) lenL[tid] = N_s[row0 + tid];
        float bo2[2];
#pragma unroll
        for(int nt=0;nt<2;++nt){ int col=wv*32+nt*16+ln15; bo2[nt] = (col<123)? b_out[col] : 0.0f; }
        __syncthreads();

#pragma unroll 1
        for (int s = 1; s < 200; ++s) {
            const u32* hp = hd32 + (s&1)*262144;
            for (int i = tid; i < 160; i += 256) xtL[i] = x[s*2560 + row0*5 + i];
            poll(hF, 7, s);

            fx4 acc[2][2] = {};
            u64 q[16], q2[16];
            LOADA(hp,0,q);
            WRITEA(q); __syncthreads();
            LOADA(hp,1,q2);
#pragma unroll
            for(int b=0;b<2;++b){
                if(b){ __syncthreads(); WRITEA(q2); __syncthreads(); }
#pragma unroll
                for(int ch=0; ch<8; ++ch){
                    bfx8 ah[2], al[2];
#pragma unroll
                    for(int rta=0;rta<2;++rta){
                        int off = (rta*16+ln15)*256 + (((ch*4+kq)^(ln15&7))<<3);
                        ah[rta]=*(const bfx8*)&AH[off]; al[rta]=*(const bfx8*)&AL[off];
                    }
#pragma unroll
                    for(int nt=0;nt<2;++nt){
                        size_t bo=(size_t)(wv*32 + nt*16 + ln15)*512 + b*256 + ch*32 + kq*8;
                        bfx8 bh=*(const bfx8*)&wOh[bo], bl=*(const bfx8*)&wOl[bo];
#pragma unroll
                        for(int rta=0;rta<2;++rta){
                            acc[rta][nt]=MFMA16(ah[rta],bh,acc[rta][nt]);
                            acc[rta][nt]=MFMA16(ah[rta],bl,acc[rta][nt]);
                            acc[rta][nt]=MFMA16(al[rta],bh,acc[rta][nt]);}}
                }
            }
#pragma unroll
            for(int rta=0;rta<2;++rta)
#pragma unroll
            for(int nt=0;nt<2;++nt)
#pragma unroll
            for(int r2=0;r2<4;++r2)
                yL[(rta*16+kq*4+r2)*132 + wv*32+nt*16+ln15] = acc[rta][nt][r2] + bo2[nt];
            __syncthreads();
            {
                const int row = tid>>3, sub = tid&7;
                const float* yr = &yL[row*132];
                const float dxv = xtL[row*5], dyv = xtL[row*5+1];
                float pm = -1e30f;
                for (int cg = sub; cg < NMIX; cg += 8) pm = fmaxf(pm, yr[cg*6]);
                pm = fmaxf(pm, __shfl_xor(pm, 1));
                pm = fmaxf(pm, __shfl_xor(pm, 2));
                pm = fmaxf(pm, __shfl_xor(pm, 4));
                float S = 0, gp = 0, gx = 0, gy = 0;
                for (int cg = sub; cg < NMIX; cg += 8) {
                    float ph = yr[cg*6], mux = yr[cg*6+1], muy = yr[cg*6+2];
                    float ssx = __expf(yr[cg*6+3]), ssy = __expf(yr[cg*6+4]);
                    float rho = tanhf(yr[cg*6+5]);
                    float e = __expf(ph - pm);
                    float zx = (dxv - mux)/ssx, zy = (dyv - muy)/ssy;
                    float om = 1.0f - rho*rho;
                    float pdf = __expf(-(zx*zx + zy*zy - 2.0f*rho*zx*zy)/(2.0f*om))
                                * (0.15915494309189535f/(ssx*ssy*sqrtf(om)));
                    S += e; gp += e*pdf; gx += e*mux; gy += e*muy;
                }
#pragma unroll
                for (int off = 1; off < 8; off <<= 1) {
                    S += __shfl_xor(S, off); gp += __shfl_xor(gp, off);
                    gx += __shfl_xor(gx, off); gy += __shfl_xor(gy, off);
                }
                if (sub == 0) {
                    const int b = row0 + row;
                    float q0v = yr[120], q1v = yr[121], q2v = yr[122];
                    int len = lenL[row];
                    int am = 0; float bv = q0v;
                    if (q1v > bv) { bv = q1v; am = 1; }
                    if (q2v > bv) { bv = q2v; am = 2; }
                    float s0,s1,s2,s3,s4;
                    if (s > len) { s0=s1=s2=s3=0.0f; s4=1.0f; }
                    else { s0=gx/S; s1=gy/S; s2=(am==0); s3=(am==1); s4=(am==2); }
                    u64* p = (u64*)sxsG + (rt*32+row)*4;
                    ast64(p,   (u64)__float_as_uint(s0) | ((u64)__float_as_uint(s1)<<32));
                    ast64(p+1, (u64)__float_as_uint(s2) | ((u64)__float_as_uint(s3)<<32));
                    ast32(((u32*)p)+4, __float_as_uint(s4));
                    float qm = fmaxf(q0v, fmaxf(q1v, q2v));
                    float lse = qm + logf(__expf(q0v-qm)+__expf(q1v-qm)+__expf(q2v-qm));
                    float pl = -(xtL[row*5+2]*(q0v-lse) + xtL[row*5+3]*(q1v-lse) + xtL[row*5+4]*(q2v-lse));
                    float ol = (s < len) ? -logf(gp/S + 1e-6f) : 0.0f;
                    float* so = out + (s-1)*2560 + b*5;
                    so[0]=s0; so[1]=s1; so[2]=s2; so[3]=s3; so[4]=s4;
                    redL[row] = pl; redL[32+row] = ol;
                }
            }
            __syncthreads();   // sxsG stores drained (vmcnt) before flag
            if (tid == 0) {
                float spl=0, sol=0;
                for (int r=0;r<32;++r){ spl+=redL[r]; sol+=redL[32+r]; }
                atomicAdd(out + 512001, spl * (1.0f/102400.0f));
                atomicAdd(out + 512000, sol * (1.0f/102400.0f));
                __hip_atomic_store(&sF[0], s, __ATOMIC_RELAXED, __HIP_MEMORY_SCOPE_AGENT);
            }
        }
    }
}

extern "C" void kernel_launch(void* const* d_in, const int* in_sizes, int n_in,
                              void* d_out_, int out_size, void* d_ws, size_t ws_size,
                              hipStream_t stream) {
    const float* x         = (const float*)d_in[0];
    const int*   N_s       = (const int*)  d_in[1];
    const float* eps       = (const float*)d_in[2];
    const float* enc_Wih_f = (const float*)d_in[3];
    const float* enc_Whh_f = (const float*)d_in[4];
    const float* enc_b_f   = (const float*)d_in[5];
    const float* enc_Wih_b = (const float*)d_in[6];
    const float* enc_Whh_b = (const float*)d_in[7];
    const float* enc_b_b   = (const float*)d_in[8];
    const float* W_mu      = (const float*)d_in[9];
    const float* b_mu      = (const float*)d_in[10];
    const float* W_logvar  = (const float*)d_in[11];
    const float* b_logvar  = (const float*)d_in[12];
    const float* W_fc_in   = (const float*)d_in[13];
    const float* b_fc_in   = (const float*)d_in[14];
    const float* dec_Wih   = (const float*)d_in[15];
    const float* dec_Whh   = (const float*)d_in[16];
    const float* dec_b     = (const float*)d_in[17];
    const float* W_out     = (const float*)d_in[18];
    const float* b_out     = (const float*)d_in[19];
    float* out = (float*)d_out_;
    float* ws  = (float*)d_ws;

    float* c_d   = ws + 0;                      // 262144
    float* zpre  = ws + 262144;                 // 1048576
    float* z     = ws + 1310720;                // 65536
    float* sxsG  = ws + 1376256;                // 4096 (16rt x 32rows x 8)
    int*   flags = (int*)(ws + 1380352);        // 2048: encF 1024 | decHF 512 | decSF 512
    u32*   hd32  = (u32*)(ws + 1382400);        // 2 x 262144
    u32*   he32  = (u32*)(ws + 1906688);        // 4 x 131072 (buf x dir)
    u16*   encT  = (u16*)(ws + 2430976);        // 4 x 262144 u16
    u16*   decT  = (u16*)(ws + 2955264);        // 2 x 1048576 u16
    u16*   woutT = (u16*)(ws + 4003840);        // 2 x 65536 u16
    int* encF  = flags;
    int* decHF = flags + 1024;
    int* decSF = flags + 1536;

    hipMemsetAsync(he32, 0, 262144 * sizeof(u32), stream);         // h(0) both dirs, buf0
    hipMemsetAsync(flags, 0, 2048 * sizeof(int), stream);
    hipMemsetAsync(out + 509440, 0, 2562 * sizeof(float), stream); // stroke row 199 + losses

    prep_split_T<<<1024, 256, 0, stream>>>(enc_Whh_f, encT,          encT + 262144,  256, 1024, 1024);
    prep_split_T<<<1024, 256, 0, stream>>>(enc_Whh_b, encT + 524288, encT + 786432,  256, 1024, 1024);
    prep_split_T<<<4096, 256, 0, stream>>>(dec_Whh,   decT,          decT + 1048576, 512, 2048, 2048);
    prep_split_T<<<256,  256, 0, stream>>>(W_out,     woutT,         woutT + 65536,  512, 123, 128);

    enc_persist<<<128, 256, 0, stream>>>(x, enc_Wih_f, enc_b_f, enc_Wih_b, enc_b_b, encT, he32, encF);
    latent1<<<32, 256, 0, stream>>>(he32, W_mu, b_mu, W_logvar, b_logvar, eps, z, out);
    latent2<<<dim3(24, 32), 256, 0, stream>>>(z, W_fc_in, b_fc_in, dec_Wih, dec_b, hd32, c_d, zpre);
    dec_persist<<<144, 256, 0, stream>>>(x, N_s, dec_Wih, b_out, decT, woutT, zpre, c_d,
                                         hd32, sxsG, out, decHF, decSF);
}